// Round 14
// baseline (1225.948 us; speedup 1.0000x reference)
//
#include <hip/hip_runtime.h>
#include <math.h>

#define NATOM 4096
#define NM    1024
#define NKR   9260      // real k-vectors (21^3 - 1)
#define KSPLIT 14
#define CHPS  22        // chunks per split
#define NCH   308       // KSPLIT*CHPS
#define KC    32
#define KPAD2 9856      // NCH*KC
#define PI_F  3.14159265358979f

typedef short v8s __attribute__((ext_vector_type(8)));   // 8 bf16 (4 VGPRs)
typedef float v4f __attribute__((ext_vector_type(4)));   // 4 fp32 acc

// ---------- k-vector data computed inline (device helper) ----------
static __device__ __forceinline__ void kdata(int t, const float* __restrict__ cell,
                                             float& kxx, float& kyy, float& kzz, float& w) {
  if (t >= NKR) { kxx = 0.f; kyy = 0.f; kzz = 0.f; w = 0.f; return; }
  int u = (t < 4630) ? t : t + 1;       // skip the all-zero triple
  int a = u / 441;
  int rem = u - a * 441;
  int b = rem / 21;
  int c = rem - b * 21;
  float na = (float)(a - 10), nb = (float)(b - 10), nc = (float)(c - 10);
  float m00=cell[0], m01=cell[1], m02=cell[2];
  float m10=cell[3], m11=cell[4], m12=cell[5];
  float m20=cell[6], m21=cell[7], m22=cell[8];
  float det = m00*(m11*m22 - m12*m21) - m01*(m10*m22 - m12*m20) + m02*(m10*m21 - m11*m20);
  float inv00 =  (m11*m22 - m12*m21) / det;
  float inv01 = -(m01*m22 - m02*m21) / det;
  float inv02 =  (m01*m12 - m02*m11) / det;
  float inv10 = -(m10*m22 - m12*m20) / det;
  float inv11 =  (m00*m22 - m02*m20) / det;
  float inv12 = -(m00*m12 - m02*m10) / det;
  float inv20 =  (m10*m21 - m11*m20) / det;
  float inv21 = -(m00*m21 - m01*m20) / det;
  float inv22 =  (m00*m11 - m01*m10) / det;
  const float twopi = 2.f * PI_F;
  kxx = twopi * (na*inv00 + nb*inv01 + nc*inv02);
  kyy = twopi * (na*inv10 + nb*inv11 + nc*inv12);
  kzz = twopi * (na*inv20 + nb*inv21 + nc*inv22);
  float k2 = kxx*kxx + kyy*kyy + kzz*kzz;
  const float sigma = 1.0f / 1.805132f;
  w = (4.f * PI_F / fabsf(det)) * __expf(-0.5f * sigma * sigma * k2) / k2;
}

// ---------- sfk: k-data + structure factors in one kernel.
__global__ __launch_bounds__(256)
void sfk(const float* __restrict__ pos, const float* __restrict__ q,
         const float* __restrict__ cell,
         float* __restrict__ kx, float* __restrict__ ky,
         float* __restrict__ kz, float* __restrict__ ksw,
         float* __restrict__ gc, float* __restrict__ gs) {
  __shared__ float red1[8][32], red2[8][32];
  const int kloc = threadIdx.x & 31;
  const int part = threadIdx.x >> 5;             // 0..7
  const int k = blockIdx.x * 32 + kloc;          // < KPAD2
  float kxx, kyy, kzz, w;
  kdata(k, cell, kxx, kyy, kzz, w);
  if (part == 0) { kx[k]=kxx; ky[k]=kyy; kz[k]=kzz; ksw[k]=sqrtf(w); }
  float sc = 0.f, ss = 0.f;
  const int j0 = NM + part * 384, j1 = j0 + 384;
  for (int j = j0; j < j1; ++j) {
    float kr = kxx*pos[3*j] + kyy*pos[3*j+1] + kzz*pos[3*j+2];
    float s, c;
    __sincosf(kr, &s, &c);
    float qj = q[j];
    sc += qj * c;
    ss += qj * s;
  }
  red1[part][kloc] = sc;
  red2[part][kloc] = ss;
  __syncthreads();
  if (part == 0) {
    float tc = 0.f, ts = 0.f;
    #pragma unroll
    for (int pp = 0; pp < 8; ++pp) { tc += red1[pp][kloc]; ts += red2[pp][kloc]; }
    gc[k] = w * tc;
    gs[k] = w * ts;
  }
}

// ----------------- B = -f at metal positions; also init r2 = ones
__global__ __launch_bounds__(256)
void fB(const float* __restrict__ pos,
        const float* __restrict__ kx, const float* __restrict__ ky,
        const float* __restrict__ kz,
        const float* __restrict__ gc, const float* __restrict__ gs,
        float* __restrict__ r1, float* __restrict__ r2) {
  int i = blockIdx.x;
  float px = pos[3*i], py = pos[3*i+1], pz = pos[3*i+2];
  float p = 0.f;
  for (int k = threadIdx.x; k < KPAD2; k += 256) {
    float kr = kx[k]*px + ky[k]*py + kz[k]*pz;
    float s, c;
    __sincosf(kr, &s, &c);
    p += gc[k]*c + gs[k]*s;
  }
  for (int o = 32; o > 0; o >>= 1) p += __shfl_down(p, o, 64);
  __shared__ float red[4];
  if ((threadIdx.x & 63) == 0) red[threadIdx.x >> 6] = p;
  __syncthreads();
  if (threadIdx.x == 0) {
    r1[i] = -(red[0] + red[1] + red[2] + red[3]);
    r2[i] = 1.f;
  }
}

// --------------- A = C W C^T + S W S^T, upper 128-tiles only (bi<=bj)
// MFMA 3-pass split-bf16 (hi*hi + hi*mid + mid*hi), per C and S.
#define PSTR 40
__global__ __launch_bounds__(256, 2)
void gemmA(const float* __restrict__ pos,
           const float* __restrict__ kx, const float* __restrict__ ky,
           const float* __restrict__ kz, const float* __restrict__ ksw,
           float* __restrict__ A) {
  __shared__ short Pl[8][128 * PSTR];
  const int blk = blockIdx.x;
  const int split = blk / 36;
  const int tt = blk - split * 36;
  int bi = 0, rem = tt;
  while (rem >= 8 - bi) { rem -= 8 - bi; ++bi; }
  const int bj = bi + rem;
  const int t = threadIdx.x;
  const int side = t >> 7;
  const int a = t & 127;
  const int atom = (side ? bj : bi) * 128 + a;
  const float px = pos[3*atom], py = pos[3*atom+1], pz = pos[3*atom+2];
  short* PC_hi = &Pl[side*4+0][a*PSTR];
  short* PC_mi = &Pl[side*4+1][a*PSTR];
  short* PS_hi = &Pl[side*4+2][a*PSTR];
  short* PS_mi = &Pl[side*4+3][a*PSTR];

  const int w = t >> 6;          // wave id 0..3 -> rows [w*32, w*32+32)
  const int lane = t & 63;
  const int ln15 = lane & 15;
  const int quad = lane >> 4;

  v4f acc[2][8];
  #pragma unroll
  for (int mt = 0; mt < 2; ++mt)
    #pragma unroll
    for (int nt = 0; nt < 8; ++nt) {
      v4f z = {0.f, 0.f, 0.f, 0.f};
      acc[mt][nt] = z;
    }

  for (int ch = split * CHPS; ch < split * CHPS + CHPS; ++ch) {
    const int kb = ch * KC;
    #pragma unroll
    for (int g = 0; g < 4; ++g) {
      v8s vch, vcm, vsh, vsm;
      #pragma unroll
      for (int j = 0; j < 8; ++j) {
        const int gk = kb + g*8 + j;
        float kr = kx[gk]*px + ky[gk]*py + kz[gk]*pz;
        float s, c;
        __sincosf(kr, &s, &c);
        float sw = ksw[gk];
        float cv = c * sw, sv = s * sw;
        unsigned cu = __float_as_uint(cv);
        float chf = __uint_as_float(cu & 0xffff0000u);
        unsigned cmu = __float_as_uint(cv - chf);
        unsigned su = __float_as_uint(sv);
        float shf = __uint_as_float(su & 0xffff0000u);
        unsigned smu = __float_as_uint(sv - shf);
        vch[j] = (short)(cu >> 16);
        vcm[j] = (short)(cmu >> 16);
        vsh[j] = (short)(su >> 16);
        vsm[j] = (short)(smu >> 16);
      }
      *(v8s*)&PC_hi[g*8] = vch;
      *(v8s*)&PC_mi[g*8] = vcm;
      *(v8s*)&PS_hi[g*8] = vsh;
      *(v8s*)&PS_mi[g*8] = vsm;
    }
    __syncthreads();
    v8s aCh[2], aCm[2], aSh[2], aSm[2];
    #pragma unroll
    for (int mt = 0; mt < 2; ++mt) {
      const int off = (w*32 + mt*16 + ln15) * PSTR + quad*8;
      aCh[mt] = *(const v8s*)&Pl[0][off];
      aCm[mt] = *(const v8s*)&Pl[1][off];
      aSh[mt] = *(const v8s*)&Pl[2][off];
      aSm[mt] = *(const v8s*)&Pl[3][off];
    }
    #pragma unroll
    for (int nt = 0; nt < 8; ++nt) {
      const int off = (nt*16 + ln15) * PSTR + quad*8;
      v8s bCh = *(const v8s*)&Pl[4][off];
      v8s bCm = *(const v8s*)&Pl[5][off];
      v8s bSh = *(const v8s*)&Pl[6][off];
      v8s bSm = *(const v8s*)&Pl[7][off];
      #pragma unroll
      for (int mt = 0; mt < 2; ++mt) {
        v4f d = acc[mt][nt];
        d = __builtin_amdgcn_mfma_f32_16x16x32_bf16(aCh[mt], bCh, d, 0, 0, 0);
        d = __builtin_amdgcn_mfma_f32_16x16x32_bf16(aCh[mt], bCm, d, 0, 0, 0);
        d = __builtin_amdgcn_mfma_f32_16x16x32_bf16(aCm[mt], bCh, d, 0, 0, 0);
        d = __builtin_amdgcn_mfma_f32_16x16x32_bf16(aSh[mt], bSh, d, 0, 0, 0);
        d = __builtin_amdgcn_mfma_f32_16x16x32_bf16(aSh[mt], bSm, d, 0, 0, 0);
        d = __builtin_amdgcn_mfma_f32_16x16x32_bf16(aSm[mt], bSh, d, 0, 0, 0);
        acc[mt][nt] = d;
      }
    }
    __syncthreads();
  }
  #pragma unroll
  for (int mt = 0; mt < 2; ++mt)
    #pragma unroll
    for (int nt = 0; nt < 8; ++nt)
      #pragma unroll
      for (int r = 0; r < 4; ++r) {
        const int row = bi*128 + w*32 + mt*16 + quad*4 + r;
        const int col = bj*128 + nt*16 + ln15;
        atomicAdd(&A[row*1024 + col], acc[mt][nt][r]);
      }
}

// ================= tile helpers (32x32, LDS stride 33) =================
static __device__ __forceinline__ void ldTile(float (*B)[33], const float* __restrict__ M,
                                              int rt, int ct, int t) {
  for (int e = t; e < 1024; e += 256)
    B[e>>5][e&31] = M[(rt*32 + (e>>5))*1024 + ct*32 + (e&31)];
}
static __device__ __forceinline__ void ldTileT(float (*B)[33], const float* __restrict__ M,
                                               int rt, int ct, int t) {
  // B = M(rt,ct) via symmetric upper copy: B[r][c] = M[ct*32+c][rt*32+r]
  for (int e = t; e < 1024; e += 256)
    B[e&31][e>>5] = M[(ct*32 + (e>>5))*1024 + rt*32 + (e&31)];
}
// current value of A-tile (q,pc): pc>=4 -> syrk'd in place (direct);
// pc<4 -> pristine gemmA output: direct iff same 128-supertile (q<4).
static __device__ __forceinline__ void ldPanelTile(float (*B)[33], const float* __restrict__ A,
                                                   int q, int pc, int t) {
  if (pc >= 4 || q < 4) ldTile(B, A, q, pc, t);
  else ldTileT(B, A, q, pc, t);
}
static __device__ __forceinline__ void ranksub(float (*O)[33], float (*X)[33], float (*Y)[33], int t) {
  const int i0 = (t >> 4) * 2, j0 = (t & 15) * 2;
  float o00=O[i0][j0], o01=O[i0][j0+1], o10=O[i0+1][j0], o11=O[i0+1][j0+1];
  for (int m = 0; m < 32; ++m) {
    float a0 = X[i0][m], a1 = X[i0+1][m];
    float b0 = Y[j0][m], b1 = Y[j0+1][m];
    o00-=a0*b0; o01-=a0*b1; o10-=a1*b0; o11-=a1*b1;
  }
  O[i0][j0]=o00; O[i0][j0+1]=o01; O[i0+1][j0]=o10; O[i0+1][j0+1]=o11;
}
static __device__ __forceinline__ void chol32(float (*D)[33], int t) {
  if (t < 32) {
    float a[32];
    #pragma unroll
    for (int m = 0; m < 32; ++m) a[m] = D[t][m];
    #pragma unroll
    for (int j = 0; j < 32; ++j) {
      float dj = __shfl(a[j], j);
      float rinv = rsqrtf(dj);
      float lj = (t == j) ? dj * rinv : a[j] * rinv;
      a[j] = lj;
      #pragma unroll
      for (int m = j + 1; m < 32; ++m) a[m] -= lj * __shfl(lj, m);
    }
    #pragma unroll
    for (int m = 0; m < 32; ++m) D[t][m] = a[m];   // upper garbage, never read
  }
}
static __device__ __forceinline__ void trsm32(float (*T)[33], float (*D)[33], int t) {
  if (t < 32) {
    #pragma unroll
    for (int cb = 0; cb < 2; ++cb) {
      const int cbase = cb * 16;
      float x[16];
      #pragma unroll
      for (int k = 0; k < 16; ++k) x[k] = T[t][cbase + k];
      for (int m = 0; m < cbase; ++m) {
        float tm = T[t][m];
        #pragma unroll
        for (int k = 0; k < 16; ++k) x[k] -= tm * D[cbase + k][m];
      }
      #pragma unroll
      for (int k = 0; k < 16; ++k) {
        float xv = x[k] * (1.0f / D[cbase + k][cbase + k]);
        x[k] = xv;
        #pragma unroll
        for (int m2 = k + 1; m2 < 16; ++m2) x[m2] -= xv * D[cbase + m2][cbase + k];
      }
      #pragma unroll
      for (int k = 0; k < 16; ++k) T[t][cbase + k] = x[k];
    }
  }
}
static __device__ __forceinline__ void fwd32(float (*D)[33], float& v1, float& v2, int t) {
  for (int j = 0; j < 32; ++j) {
    float invd = 1.f / D[j][j];
    float Lij = D[t][j];
    float x1 = __shfl(v1, j) * invd;
    float x2 = __shfl(v2, j) * invd;
    if (t == j)      { v1 = x1; v2 = x2; }
    else if (t > j)  { v1 -= Lij * x1; v2 -= Lij * x2; }
  }
}
static __device__ __forceinline__ void stTileFull(float* __restrict__ L, float (*B)[33],
                                                  int rt, int ct, int t) {
  for (int e = t; e < 1024; e += 256)
    L[(rt*32 + (e>>5))*1024 + ct*32 + (e&31)] = B[e>>5][e&31];
}
static __device__ __forceinline__ void stTileLow(float* __restrict__ L, float (*B)[33],
                                                 int rt, int ct, int t) {
  for (int e = t; e < 1024; e += 256) {
    int i = e>>5, j = e&31;
    if (i >= j) L[(rt*32 + i)*1024 + ct*32 + j] = B[i][j];
  }
}

// ============ step2(P): columns p0=2P, p1=2P+1 in ONE launch ============
// Panel-A blocks  [0,nbA):        tile (q,p0); diag (b==0) also y_p0.
// Panel-B blocks  [nbA,nbA+nbB):  tile (q,p1); replays D_p0->L(p1,p0)->D_p1
//                                 in-block (redundant, bitwise-identical);
//                                 also applies BOTH r-updates for row q.
// Syrk blocks     rest:           apply cols z0=2P-2, z1=2P-1 to trailing
//                                 A(qi,qj>=p0+2) in place.
// L lives in separate Lmat (no in-place write -> no intra-launch races).
__global__ __launch_bounds__(256)
void step2(float* __restrict__ A, float* __restrict__ L,
           float* __restrict__ r1, float* __restrict__ r2,
           float* __restrict__ y1g, float* __restrict__ y2g, int P) {
  __shared__ float DA[32][33], DB[32][33], RB[32][33], OWN[32][33], LQ[32][33];
  __shared__ float Z0[32][33], Z1[32][33], W0[32][33], W1[32][33], V0[32][33], V1[32][33];
  __shared__ float ya1[32], ya2[32], yb1[32], yb2[32];
  const int t = threadIdx.x;
  const int p0 = 2*P, p1 = p0 + 1;
  const int z0 = p0 - 2, z1 = p0 - 1;
  const int nbA = 32 - p0, nbB = 31 - p0;
  const int b = blockIdx.x;
  const int i0 = (t >> 4) * 2, j0 = (t & 15) * 2;

  if (b >= nbA + nbB) {
    // ---------------- syrk role (P >= 1 only) ----------------
    int rem = b - (nbA + nbB), a = 0;
    while (rem >= a + 1) { rem -= (a + 1); ++a; }
    const int qi = p0 + 2 + a, qj = p0 + 2 + rem;      // qi >= qj >= p0+2
    ldTile(Z0, L, qi, z0, t); ldTile(Z1, L, qi, z1, t);
    ldTile(W0, L, qj, z0, t); ldTile(W1, L, qj, z1, t);
    float o[2][2];
    if (P == 1 && (qi >> 2) != (qj >> 2)) {
      #pragma unroll
      for (int ii = 0; ii < 2; ++ii)
        #pragma unroll
        for (int jj = 0; jj < 2; ++jj)
          o[ii][jj] = A[(qj*32 + j0+jj)*1024 + qi*32 + i0+ii];
    } else {
      #pragma unroll
      for (int ii = 0; ii < 2; ++ii)
        #pragma unroll
        for (int jj = 0; jj < 2; ++jj)
          o[ii][jj] = A[(qi*32+i0+ii)*1024 + qj*32 + j0+jj];
    }
    __syncthreads();
    for (int m = 0; m < 32; ++m) {      // col z0 first (preserve order)
      float a0 = Z0[i0][m], a1 = Z0[i0+1][m];
      float b0 = W0[j0][m], b1 = W0[j0+1][m];
      o[0][0]-=a0*b0; o[0][1]-=a0*b1; o[1][0]-=a1*b0; o[1][1]-=a1*b1;
    }
    for (int m = 0; m < 32; ++m) {      // then col z1
      float a0 = Z1[i0][m], a1 = Z1[i0+1][m];
      float b0 = W1[j0][m], b1 = W1[j0+1][m];
      o[0][0]-=a0*b0; o[0][1]-=a0*b1; o[1][0]-=a1*b0; o[1][1]-=a1*b1;
    }
    #pragma unroll
    for (int ii = 0; ii < 2; ++ii)
      #pragma unroll
      for (int jj = 0; jj < 2; ++jj)
        A[(qi*32+i0+ii)*1024 + qj*32 + j0+jj] = o[ii][jj];
    return;
  }

  if (b < nbA) {
    // ---------------- Panel-A: tile (q, p0) ----------------
    const int q = p0 + b;
    ldTile(DA, A, p0, p0, t);
    if (P >= 1) { ldTile(Z0, L, p0, z0, t); ldTile(Z1, L, p0, z1, t); }
    if (b > 0) {
      ldPanelTile(OWN, A, q, p0, t);
      if (P >= 1) { ldTile(W0, L, q, z0, t); ldTile(W1, L, q, z1, t); }
    }
    __syncthreads();
    if (P >= 1) {
      ranksub(DA, Z0, Z0, t);
      ranksub(DA, Z1, Z1, t);
      if (b > 0) { ranksub(OWN, W0, Z0, t); ranksub(OWN, W1, Z1, t); }
      __syncthreads();
    }
    chol32(DA, t);
    __syncthreads();
    if (b == 0) {
      stTileLow(L, DA, p0, p0, t);
      if (t < 32) {
        float v1 = r1[p0*32 + t], v2 = r2[p0*32 + t];
        fwd32(DA, v1, v2, t);
        y1g[p0*32 + t] = v1; y2g[p0*32 + t] = v2;
      }
    } else {
      trsm32(OWN, DA, t);
      __syncthreads();
      stTileFull(L, OWN, q, p0, t);
    }
    return;
  }

  // ---------------- Panel-B: tile (q, p1) ----------------
  const int bb = b - nbA;
  const int q = p1 + bb;
  ldTile(DA, A, p0, p0, t);
  ldTile(DB, A, p1, p1, t);
  ldPanelTile(RB, A, p1, p0, t);
  if (P >= 1) {
    ldTile(Z0, L, p0, z0, t); ldTile(Z1, L, p0, z1, t);   // L(p0, z)
    ldTile(W0, L, p1, z0, t); ldTile(W1, L, p1, z1, t);   // L(p1, z)
  }
  __syncthreads();
  if (P >= 1) {
    ranksub(DA, Z0, Z0, t); ranksub(DA, Z1, Z1, t);
    ranksub(RB, W0, Z0, t); ranksub(RB, W1, Z1, t);
    ranksub(DB, W0, W0, t); ranksub(DB, W1, W1, t);
    __syncthreads();
  }
  chol32(DA, t);
  __syncthreads();
  trsm32(RB, DA, t);          // RB = L(p1,p0)
  __syncthreads();
  ranksub(DB, RB, RB, t);     // DB -= RB RB^T  (col p0)
  __syncthreads();
  chol32(DB, t);
  __syncthreads();
  // y0 redundant; yB = r[p1] - RB*y0 ; y1 = solve(DB, yB)
  if (t < 32) {
    float v1 = r1[p0*32 + t], v2 = r2[p0*32 + t];
    fwd32(DA, v1, v2, t);
    ya1[t] = v1; ya2[t] = v2;
  }
  __syncthreads();
  if (t < 32) {
    float u1 = r1[p1*32 + t], u2 = r2[p1*32 + t];
    for (int j = 0; j < 32; ++j) { float lv = RB[t][j]; u1 -= lv * ya1[j]; u2 -= lv * ya2[j]; }
    fwd32(DB, u1, u2, t);
    if (bb == 0) { y1g[p1*32 + t] = u1; y2g[p1*32 + t] = u2; }
    yb1[t] = u1; yb2[t] = u2;
  }
  __syncthreads();
  if (bb == 0) {
    stTileLow(L, DB, p1, p1, t);
    return;                    // diag Panel-B: L(p1,p0) stored by Panel-A b=1
  }
  // off-diagonal Panel-B
  ldPanelTile(OWN, A, q, p1, t);
  ldPanelTile(LQ,  A, q, p0, t);
  if (P >= 1) { ldTile(V0, L, q, z0, t); ldTile(V1, L, q, z1, t); }
  __syncthreads();
  if (P >= 1) {
    ranksub(LQ,  V0, Z0, t);  ranksub(LQ,  V1, Z1, t);    // cols z0, z1
    ranksub(OWN, V0, W0, t);  ranksub(OWN, V1, W1, t);
    __syncthreads();
  }
  trsm32(LQ, DA, t);           // LQ = L(q,p0)  (redundant with Panel-A)
  __syncthreads();
  ranksub(OWN, LQ, RB, t);     // col p0
  __syncthreads();
  trsm32(OWN, DB, t);          // OWN = L(q,p1)
  __syncthreads();
  stTileFull(L, OWN, q, p1, t);
  // r-updates for row q: r[q] -= L(q,p0) y0, then -= L(q,p1) y1
  if (t < 32) {
    float a1 = 0.f, a2 = 0.f;
    for (int j = 0; j < 32; ++j) { float lv = LQ[t][j]; a1 += lv * ya1[j]; a2 += lv * ya2[j]; }
    float c1 = 0.f, c2 = 0.f;
    for (int j = 0; j < 32; ++j) { float lv = OWN[t][j]; c1 += lv * yb1[j]; c2 += lv * yb2[j]; }
    r1[q*32 + t] -= a1; r1[q*32 + t] -= c1;
    r2[q*32 + t] -= a2; r2[q*32 + t] -= c2;
  }
}

// ---- backward solve, 256-wide panel (reads Lmat)
__global__ __launch_bounds__(256)
void bwd_solve(const float* __restrict__ L, float* __restrict__ y1g, float* __restrict__ y2g,
               const float* __restrict__ qin, float* __restrict__ out, int S, int finalize) {
  __shared__ float D[64][65];
  __shared__ float x1s[64], x2s[64];
  __shared__ float rs1[4], rs2[4];
  const int t = threadIdx.x;
  const int base0 = S * 256;
  for (int j3 = 3; j3 >= 0; --j3) {
    const int base = base0 + j3 * 64;
    for (int e = t; e < 4096; e += 256)
      D[e>>6][e&63] = L[(base + (e>>6))*1024 + base + (e&63)];
    __syncthreads();
    if (t < 64) {
      float v1 = y1g[base + t], v2 = y2g[base + t];
      for (int i = 63; i >= 0; --i) {
        float invd = 1.f / D[i][i];
        float x1 = __shfl(v1, i) * invd;
        float x2 = __shfl(v2, i) * invd;
        float Lim = D[i][t];
        if (t == i)      { v1 = x1; v2 = x2; }
        else if (t < i)  { v1 -= Lim * x1; v2 -= Lim * x2; }
      }
      y1g[base + t] = v1; y2g[base + t] = v2;
      x1s[t] = v1; x2s[t] = v2;
    }
    __syncthreads();
    const int nup = j3 * 64;
    for (int rr = t; rr < nup; rr += 256) {
      float a1 = 0.f, a2 = 0.f;
      #pragma unroll 8
      for (int jj = 0; jj < 64; ++jj) {
        float lv = L[(base+jj)*1024 + base0 + rr];
        a1 += lv * x1s[jj];
        a2 += lv * x2s[jj];
      }
      y1g[base0+rr] -= a1; y2g[base0+rr] -= a2;
    }
    __syncthreads();
  }
  if (finalize) {
    float s1 = 0.f, s2 = 0.f;
    for (int e = t; e < 1024; e += 256) { s1 += y1g[e]; s2 += y2g[e]; }
    for (int o = 32; o > 0; o >>= 1) { s1 += __shfl_down(s1, o, 64); s2 += __shfl_down(s2, o, 64); }
    if ((t & 63) == 0) { rs1[t >> 6] = s1; rs2[t >> 6] = s2; }
    __syncthreads();
    const float lam = (rs1[0]+rs1[1]+rs1[2]+rs1[3]) / (rs2[0]+rs2[1]+rs2[2]+rs2[3]);
    for (int e = t; e < 1024; e += 256) out[e] = y1g[e] - lam * y2g[e];
    for (int e = NM + t; e < NATOM; e += 256) out[e] = qin[e];
  }
}

// ---- backward update: y[0..256S) -= L(panel S rows, cols)^T x_S, parallel.
__global__ __launch_bounds__(256)
void bwd_upd(const float* __restrict__ L, float* __restrict__ y1g, float* __restrict__ y2g, int S) {
  __shared__ float x1s[256], x2s[256];
  __shared__ float p1[4][64], p2[4][64];
  const int t = threadIdx.x;
  const int rbase = blockIdx.x * 64;             // < 256*S
  const int r = t & 63;
  const int slice = t >> 6;                      // 0..3
  x1s[t] = y1g[S*256 + t];
  x2s[t] = y2g[S*256 + t];
  __syncthreads();
  float a1 = 0.f, a2 = 0.f;
  for (int j = slice*64; j < slice*64 + 64; ++j) {
    float lv = L[(S*256 + j)*1024 + rbase + r];
    a1 += lv * x1s[j];
    a2 += lv * x2s[j];
  }
  p1[slice][r] = a1; p2[slice][r] = a2;
  __syncthreads();
  if (t < 64) {
    y1g[rbase + t] -= p1[0][t] + p1[1][t] + p1[2][t] + p1[3][t];
    y2g[rbase + t] -= p2[0][t] + p2[1][t] + p2[2][t] + p2[3][t];
  }
}

// --------------------------------------------------------------- launch
extern "C" void kernel_launch(void* const* d_in, const int* in_sizes, int n_in,
                              void* d_out, int out_size, void* d_ws, size_t ws_size,
                              hipStream_t stream) {
  const float* pos  = (const float*)d_in[0];
  const float* q    = (const float*)d_in[1];
  const float* cell = (const float*)d_in[2];
  float* out = (float*)d_out;

  float* ws  = (float*)d_ws;
  float* A   = ws;                                   // 1,048,576 floats
  float* Lm  = ws + 1048576;                         // 1,048,576 floats (L factor)
  float* kx  = Lm + 1048576;
  float* ky  = kx + KPAD2;
  float* kz  = ky + KPAD2;
  float* ksw = kz + KPAD2;
  float* gc  = ksw + KPAD2;                          // KPAD2
  float* gs  = gc + KPAD2;                           // KPAD2
  float* r1  = gs + KPAD2;                           // 1024
  float* r2  = r1 + 1024;                            // 1024
  float* y1g = r2 + 1024;                            // 1024
  float* y2g = y1g + 1024;                           // 1024

  sfk<<<NCH, 256, 0, stream>>>(pos, q, cell, kx, ky, kz, ksw, gc, gs);
  fB<<<NM, 256, 0, stream>>>(pos, kx, ky, kz, gc, gs, r1, r2);
  hipMemsetAsync(A, 0, 1024 * 1024 * sizeof(float), stream);
  gemmA<<<36 * KSPLIT, 256, 0, stream>>>(pos, kx, ky, kz, ksw, A);
  for (int P = 0; P < 16; ++P) {
    const int s = 30 - 2*P;
    const int grid = (63 - 4*P) + ((P >= 1) ? s * (s + 1) / 2 : 0);
    step2<<<grid, 256, 0, stream>>>(A, Lm, r1, r2, y1g, y2g, P);
  }
  for (int S = 3; S >= 0; --S) {
    bwd_solve<<<1, 256, 0, stream>>>(Lm, y1g, y2g, q, out, S, S == 0);
    if (S > 0) bwd_upd<<<4 * S, 256, 0, stream>>>(Lm, y1g, y2g, S);
  }
}

// Round 15
// 918.954 us; speedup vs baseline: 1.3341x; 1.3341x over previous
//
#include <hip/hip_runtime.h>
#include <math.h>

#define NATOM 4096
#define NM    1024
#define NKR   9260      // real k-vectors (21^3 - 1)
#define KSPLIT 14
#define CHPS  22        // chunks per split
#define NCH   308       // KSPLIT*CHPS
#define KC    32
#define KPAD2 9856      // NCH*KC
#define PI_F  3.14159265358979f

typedef short v8s __attribute__((ext_vector_type(8)));   // 8 bf16 (4 VGPRs)
typedef float v4f __attribute__((ext_vector_type(4)));   // 4 fp32

// ---------- k-vector data computed inline (device helper) ----------
static __device__ __forceinline__ void kdata(int t, const float* __restrict__ cell,
                                             float& kxx, float& kyy, float& kzz, float& w) {
  if (t >= NKR) { kxx = 0.f; kyy = 0.f; kzz = 0.f; w = 0.f; return; }
  int u = (t < 4630) ? t : t + 1;       // skip the all-zero triple
  int a = u / 441;
  int rem = u - a * 441;
  int b = rem / 21;
  int c = rem - b * 21;
  float na = (float)(a - 10), nb = (float)(b - 10), nc = (float)(c - 10);
  float m00=cell[0], m01=cell[1], m02=cell[2];
  float m10=cell[3], m11=cell[4], m12=cell[5];
  float m20=cell[6], m21=cell[7], m22=cell[8];
  float det = m00*(m11*m22 - m12*m21) - m01*(m10*m22 - m12*m20) + m02*(m10*m21 - m11*m20);
  float inv00 =  (m11*m22 - m12*m21) / det;
  float inv01 = -(m01*m22 - m02*m21) / det;
  float inv02 =  (m01*m12 - m02*m11) / det;
  float inv10 = -(m10*m22 - m12*m20) / det;
  float inv11 =  (m00*m22 - m02*m20) / det;
  float inv12 = -(m00*m12 - m02*m10) / det;
  float inv20 =  (m10*m21 - m11*m20) / det;
  float inv21 = -(m00*m21 - m01*m20) / det;
  float inv22 =  (m00*m11 - m01*m10) / det;
  const float twopi = 2.f * PI_F;
  kxx = twopi * (na*inv00 + nb*inv01 + nc*inv02);
  kyy = twopi * (na*inv10 + nb*inv11 + nc*inv12);
  kzz = twopi * (na*inv20 + nb*inv21 + nc*inv22);
  float k2 = kxx*kxx + kyy*kyy + kzz*kzz;
  const float sigma = 1.0f / 1.805132f;
  w = (4.f * PI_F / fabsf(det)) * __expf(-0.5f * sigma * sigma * k2) / k2;
}

// ---------- sfk: k-data + structure factors in one kernel.
__global__ __launch_bounds__(256)
void sfk(const float* __restrict__ pos, const float* __restrict__ q,
         const float* __restrict__ cell,
         float* __restrict__ kx, float* __restrict__ ky,
         float* __restrict__ kz, float* __restrict__ ksw,
         float* __restrict__ gc, float* __restrict__ gs) {
  __shared__ float red1[8][32], red2[8][32];
  const int kloc = threadIdx.x & 31;
  const int part = threadIdx.x >> 5;             // 0..7
  const int k = blockIdx.x * 32 + kloc;          // < KPAD2
  float kxx, kyy, kzz, w;
  kdata(k, cell, kxx, kyy, kzz, w);
  if (part == 0) { kx[k]=kxx; ky[k]=kyy; kz[k]=kzz; ksw[k]=sqrtf(w); }
  float sc = 0.f, ss = 0.f;
  const int j0 = NM + part * 384, j1 = j0 + 384;
  for (int j = j0; j < j1; ++j) {
    float kr = kxx*pos[3*j] + kyy*pos[3*j+1] + kzz*pos[3*j+2];
    float s, c;
    __sincosf(kr, &s, &c);
    float qj = q[j];
    sc += qj * c;
    ss += qj * s;
  }
  red1[part][kloc] = sc;
  red2[part][kloc] = ss;
  __syncthreads();
  if (part == 0) {
    float tc = 0.f, ts = 0.f;
    #pragma unroll
    for (int pp = 0; pp < 8; ++pp) { tc += red1[pp][kloc]; ts += red2[pp][kloc]; }
    gc[k] = w * tc;
    gs[k] = w * ts;
  }
}

// ----------------- B = -f at metal positions; also init r2 = ones
__global__ __launch_bounds__(256)
void fB(const float* __restrict__ pos,
        const float* __restrict__ kx, const float* __restrict__ ky,
        const float* __restrict__ kz,
        const float* __restrict__ gc, const float* __restrict__ gs,
        float* __restrict__ r1, float* __restrict__ r2) {
  int i = blockIdx.x;
  float px = pos[3*i], py = pos[3*i+1], pz = pos[3*i+2];
  float p = 0.f;
  for (int k = threadIdx.x; k < KPAD2; k += 256) {
    float kr = kx[k]*px + ky[k]*py + kz[k]*pz;
    float s, c;
    __sincosf(kr, &s, &c);
    p += gc[k]*c + gs[k]*s;
  }
  for (int o = 32; o > 0; o >>= 1) p += __shfl_down(p, o, 64);
  __shared__ float red[4];
  if ((threadIdx.x & 63) == 0) red[threadIdx.x >> 6] = p;
  __syncthreads();
  if (threadIdx.x == 0) {
    r1[i] = -(red[0] + red[1] + red[2] + red[3]);
    r2[i] = 1.f;
  }
}

// --------------- A = C W C^T + S W S^T, upper 128-tiles only (bi<=bj)
// MFMA 3-pass split-bf16. XOR-swizzled k-group slot: slot = g ^ ((row>>3)&3)
// breaks the 8-way bank conflict on staging writes (stride-20dw lanes a,a+8..
// hit the same quad); readers apply the identical formula -> bit-identical.
#define PSTR 40
__global__ __launch_bounds__(256, 2)
void gemmA(const float* __restrict__ pos,
           const float* __restrict__ kx, const float* __restrict__ ky,
           const float* __restrict__ kz, const float* __restrict__ ksw,
           float* __restrict__ A) {
  __shared__ short Pl[8][128 * PSTR];
  const int blk = blockIdx.x;
  const int split = blk / 36;
  const int tt = blk - split * 36;
  int bi = 0, rem = tt;
  while (rem >= 8 - bi) { rem -= 8 - bi; ++bi; }
  const int bj = bi + rem;
  const int t = threadIdx.x;
  const int side = t >> 7;
  const int a = t & 127;
  const int atom = (side ? bj : bi) * 128 + a;
  const float px = pos[3*atom], py = pos[3*atom+1], pz = pos[3*atom+2];
  const int axor = (a >> 3) & 3;
  short* PC_hi = &Pl[side*4+0][a*PSTR];
  short* PC_mi = &Pl[side*4+1][a*PSTR];
  short* PS_hi = &Pl[side*4+2][a*PSTR];
  short* PS_mi = &Pl[side*4+3][a*PSTR];

  const int w = t >> 6;          // wave id 0..3 -> rows [w*32, w*32+32)
  const int lane = t & 63;
  const int ln15 = lane & 15;
  const int quad = lane >> 4;

  v4f acc[2][8];
  #pragma unroll
  for (int mt = 0; mt < 2; ++mt)
    #pragma unroll
    for (int nt = 0; nt < 8; ++nt) {
      v4f z = {0.f, 0.f, 0.f, 0.f};
      acc[mt][nt] = z;
    }

  for (int ch = split * CHPS; ch < split * CHPS + CHPS; ++ch) {
    const int kb = ch * KC;
    #pragma unroll
    for (int g = 0; g < 4; ++g) {
      v8s vch, vcm, vsh, vsm;
      #pragma unroll
      for (int j = 0; j < 8; ++j) {
        const int gk = kb + g*8 + j;
        float kr = kx[gk]*px + ky[gk]*py + kz[gk]*pz;
        float s, c;
        __sincosf(kr, &s, &c);
        float sw = ksw[gk];
        float cv = c * sw, sv = s * sw;
        unsigned cu = __float_as_uint(cv);
        float chf = __uint_as_float(cu & 0xffff0000u);
        unsigned cmu = __float_as_uint(cv - chf);
        unsigned su = __float_as_uint(sv);
        float shf = __uint_as_float(su & 0xffff0000u);
        unsigned smu = __float_as_uint(sv - shf);
        vch[j] = (short)(cu >> 16);
        vcm[j] = (short)(cmu >> 16);
        vsh[j] = (short)(su >> 16);
        vsm[j] = (short)(smu >> 16);
      }
      const int slot = (g ^ axor) * 8;
      *(v8s*)&PC_hi[slot] = vch;
      *(v8s*)&PC_mi[slot] = vcm;
      *(v8s*)&PS_hi[slot] = vsh;
      *(v8s*)&PS_mi[slot] = vsm;
    }
    __syncthreads();
    v8s aCh[2], aCm[2], aSh[2], aSm[2];
    #pragma unroll
    for (int mt = 0; mt < 2; ++mt) {
      const int row = w*32 + mt*16 + ln15;
      const int off = row * PSTR + (quad ^ ((row >> 3) & 3)) * 8;
      aCh[mt] = *(const v8s*)&Pl[0][off];
      aCm[mt] = *(const v8s*)&Pl[1][off];
      aSh[mt] = *(const v8s*)&Pl[2][off];
      aSm[mt] = *(const v8s*)&Pl[3][off];
    }
    #pragma unroll
    for (int nt = 0; nt < 8; ++nt) {
      const int row = nt*16 + ln15;
      const int off = row * PSTR + (quad ^ ((row >> 3) & 3)) * 8;
      v8s bCh = *(const v8s*)&Pl[4][off];
      v8s bCm = *(const v8s*)&Pl[5][off];
      v8s bSh = *(const v8s*)&Pl[6][off];
      v8s bSm = *(const v8s*)&Pl[7][off];
      #pragma unroll
      for (int mt = 0; mt < 2; ++mt) {
        v4f d = acc[mt][nt];
        d = __builtin_amdgcn_mfma_f32_16x16x32_bf16(aCh[mt], bCh, d, 0, 0, 0);
        d = __builtin_amdgcn_mfma_f32_16x16x32_bf16(aCh[mt], bCm, d, 0, 0, 0);
        d = __builtin_amdgcn_mfma_f32_16x16x32_bf16(aCm[mt], bCh, d, 0, 0, 0);
        d = __builtin_amdgcn_mfma_f32_16x16x32_bf16(aSh[mt], bSh, d, 0, 0, 0);
        d = __builtin_amdgcn_mfma_f32_16x16x32_bf16(aSh[mt], bSm, d, 0, 0, 0);
        d = __builtin_amdgcn_mfma_f32_16x16x32_bf16(aSm[mt], bSh, d, 0, 0, 0);
        acc[mt][nt] = d;
      }
    }
    __syncthreads();
  }
  #pragma unroll
  for (int mt = 0; mt < 2; ++mt)
    #pragma unroll
    for (int nt = 0; nt < 8; ++nt)
      #pragma unroll
      for (int r = 0; r < 4; ++r) {
        const int row = bi*128 + w*32 + mt*16 + quad*4 + r;
        const int col = bj*128 + nt*16 + ln15;
        atomicAdd(&A[row*1024 + col], acc[mt][nt][r]);
      }
}

// ============ step(p): b=32 panels, fused lazy-syrk + panel (R12 logic,
// LDS stride 36 + float4 tile I/O; identical math/order) ============
__global__ __launch_bounds__(256)
void step(float* __restrict__ A, const float* __restrict__ r1, const float* __restrict__ r2,
          float* __restrict__ ru1, float* __restrict__ ru2,
          float* __restrict__ y1g, float* __restrict__ y2g, int p) {
  __shared__ __align__(16) float D[32][36];
  __shared__ __align__(16) float T[32][36];
  __shared__ float y1s[32], y2s[32];
  const int t = threadIdx.x;
  const int nb = 32 - p;
  const int i0 = (t >> 4) * 2, j0 = (t & 15) * 2;   // 2x2 micro-tile
  const int lr = t >> 3, lc = (t & 7) * 4;          // float4 tile coords

  if ((int)blockIdx.x >= nb) {
    // ---------------- syrk role (only launched for p >= 1) ----------------
    int rem = blockIdx.x - nb, a = 0;
    while (rem >= a + 1) { rem -= (a + 1); ++a; }
    const int qi = p + 1 + a, qj = p + 1 + rem;     // qi >= qj >= p+1
    *(v4f*)&D[lr][lc] = *(const v4f*)&A[(qi*32+lr)*1024 + (p-1)*32 + lc];  // L(qi,p-1)
    *(v4f*)&T[lr][lc] = *(const v4f*)&A[(qj*32+lr)*1024 + (p-1)*32 + lc];  // L(qj,p-1)
    float o[2][2];
    if (p == 1 && (qi >> 2) != (qj >> 2)) {
      #pragma unroll
      for (int ii = 0; ii < 2; ++ii)
        #pragma unroll
        for (int jj = 0; jj < 2; ++jj)
          o[ii][jj] = A[(qj*32 + j0+jj)*1024 + qi*32 + i0+ii];
    } else {
      #pragma unroll
      for (int ii = 0; ii < 2; ++ii)
        #pragma unroll
        for (int jj = 0; jj < 2; ++jj)
          o[ii][jj] = A[(qi*32+i0+ii)*1024 + qj*32 + j0+jj];
    }
    __syncthreads();
    for (int m = 0; m < 32; ++m) {
      float a0 = D[i0][m], a1 = D[i0+1][m];
      float b0 = T[j0][m], b1 = T[j0+1][m];
      o[0][0]-=a0*b0; o[0][1]-=a0*b1;
      o[1][0]-=a1*b0; o[1][1]-=a1*b1;
    }
    #pragma unroll
    for (int ii = 0; ii < 2; ++ii)
      #pragma unroll
      for (int jj = 0; jj < 2; ++jj)
        A[(qi*32+i0+ii)*1024 + qj*32 + j0+jj] = o[ii][jj];
    return;
  }

  // ---------------- panel role: tile (q, p) ----------------
  const int b = blockIdx.x;
  const int q = p + b;
  if (p == 0) {
    *(v4f*)&D[lr][lc] = *(const v4f*)&A[lr*1024 + lc];                    // A(0,0)
    if (b > 0) {
      if (q < 4) {
        *(v4f*)&T[lr][lc] = *(const v4f*)&A[(q*32+lr)*1024 + lc];         // direct
      } else {
        for (int e = t; e < 1024; e += 256)
          T[e&31][e>>5] = A[(e>>5)*1024 + q*32 + (e&31)];                 // A(0,q)^T
      }
    }
    __syncthreads();
  } else {
    *(v4f*)&D[lr][lc] = *(const v4f*)&A[(p*32+lr)*1024 + (p-1)*32 + lc];  // L(p,p-1)
    if (b > 0)
      *(v4f*)&T[lr][lc] = *(const v4f*)&A[(q*32+lr)*1024 + (p-1)*32 + lc];// L(q,p-1)
    __syncthreads();
    // diag update o1 = A(p,p) - L(p,p-1) L(p,p-1)^T
    float o1[2][2];
    #pragma unroll
    for (int ii = 0; ii < 2; ++ii)
      #pragma unroll
      for (int jj = 0; jj < 2; ++jj)
        o1[ii][jj] = A[(p*32+i0+ii)*1024 + p*32 + j0+jj];
    for (int m = 0; m < 32; ++m) {
      float a0 = D[i0][m], a1 = D[i0+1][m];
      float b0 = D[j0][m], b1 = D[j0+1][m];
      o1[0][0]-=a0*b0; o1[0][1]-=a0*b1;
      o1[1][0]-=a1*b0; o1[1][1]-=a1*b1;
    }
    float o2[2][2];
    if (b > 0) {
      // own-tile update o2 = A(q,p) - L(q,p-1) L(p,p-1)^T
      if (p == 1 && (q >> 2) != 0) {
        #pragma unroll
        for (int ii = 0; ii < 2; ++ii)
          #pragma unroll
          for (int jj = 0; jj < 2; ++jj)
            o2[ii][jj] = A[(1*32 + j0+jj)*1024 + q*32 + i0+ii];
      } else {
        #pragma unroll
        for (int ii = 0; ii < 2; ++ii)
          #pragma unroll
          for (int jj = 0; jj < 2; ++jj)
            o2[ii][jj] = A[(q*32+i0+ii)*1024 + p*32 + j0+jj];
      }
      for (int m = 0; m < 32; ++m) {
        float a0 = T[i0][m], a1 = T[i0+1][m];
        float b0 = D[j0][m], b1 = D[j0+1][m];
        o2[0][0]-=a0*b0; o2[0][1]-=a0*b1;
        o2[1][0]-=a1*b0; o2[1][1]-=a1*b1;
      }
    }
    __syncthreads();   // done reading D,T as L-tiles
    #pragma unroll
    for (int ii = 0; ii < 2; ++ii)
      #pragma unroll
      for (int jj = 0; jj < 2; ++jj)
        D[i0+ii][j0+jj] = o1[ii][jj];
    if (b > 0) {
      #pragma unroll
      for (int ii = 0; ii < 2; ++ii)
        #pragma unroll
        for (int jj = 0; jj < 2; ++jj)
          T[i0+ii][j0+jj] = o2[ii][jj];
    }
    __syncthreads();
  }

  // ---- wave-register Cholesky of D (lanes 0..31; lane = row) ----
  if (t < 32) {
    float a[32];
    #pragma unroll
    for (int m = 0; m < 32; ++m) a[m] = D[t][m];
    #pragma unroll
    for (int j = 0; j < 32; ++j) {
      float dj = __shfl(a[j], j);
      float rinv = rsqrtf(dj);
      float lj = (t == j) ? dj * rinv : a[j] * rinv;
      a[j] = lj;
      #pragma unroll
      for (int m = j + 1; m < 32; ++m)
        a[m] -= lj * __shfl(lj, m);
    }
    #pragma unroll
    for (int m = 0; m < 32; ++m) D[t][m] = a[m];  // upper garbage, never read
  }
  __syncthreads();
  if (b == 0) {
    for (int e = t; e < 1024; e += 256) {
      int i = e >> 5, j = e & 31;
      if (i >= j) A[(p*32+i)*1024 + p*32 + j] = D[i][j];
    }
  } else {
    // ---- blocked-register TRSM: solve X L^T = T (lanes 0..31 = rows) ----
    if (t < 32) {
      #pragma unroll
      for (int cb = 0; cb < 2; ++cb) {
        const int cbase = cb * 16;
        float x[16];
        #pragma unroll
        for (int k = 0; k < 16; ++k) x[k] = T[t][cbase + k];
        for (int m = 0; m < cbase; ++m) {
          float tm = T[t][m];                       // own solved value
          #pragma unroll
          for (int k = 0; k < 16; ++k)
            x[k] -= tm * D[cbase + k][m];           // broadcast L read
        }
        #pragma unroll
        for (int k = 0; k < 16; ++k) {
          float xv = x[k] * (1.0f / D[cbase + k][cbase + k]);
          x[k] = xv;
          #pragma unroll
          for (int m2 = k + 1; m2 < 16; ++m2)
            x[m2] -= xv * D[cbase + m2][cbase + k];
        }
        #pragma unroll
        for (int k = 0; k < 16; ++k) T[t][cbase + k] = x[k];
      }
    }
    __syncthreads();
    *(v4f*)&A[(q*32+lr)*1024 + p*32 + lc] = *(const v4f*)&T[lr][lc];
  }
  __syncthreads();
  // forward solve y_p = L_pp^{-1} r_p (redundant per block, lanes 0..31)
  if (t < 32) {
    float v1 = r1[p*32 + t], v2 = r2[p*32 + t];
    for (int j = 0; j < 32; ++j) {
      float invd = 1.f / D[j][j];
      float Lij = D[t][j];
      float x1 = __shfl(v1, j) * invd;
      float x2 = __shfl(v2, j) * invd;
      if (t == j)      { v1 = x1; v2 = x2; }
      else if (t > j)  { v1 -= Lij * x1; v2 -= Lij * x2; }
    }
    y1s[t] = v1; y2s[t] = v2;
    if (b == 0) { y1g[p*32 + t] = v1; y2g[p*32 + t] = v2; }
  }
  __syncthreads();
  if (b > 0 && t < 32) {
    float a1 = 0.f, a2 = 0.f;
    for (int j = 0; j < 32; ++j) {
      float lv = T[t][j];
      a1 += lv * y1s[j];
      a2 += lv * y2s[j];
    }
    ru1[q*32 + t] -= a1;
    ru2[q*32 + t] -= a2;
  }
}

// --------- backward solve (L^T x = y, 2 RHS), lambda, final output (R12)
__global__ __launch_bounds__(1024)
void bwd_out(const float* __restrict__ A, float* __restrict__ y1g, float* __restrict__ y2g,
             const float* __restrict__ qin, float* __restrict__ out) {
  __shared__ float D[64][65];
  __shared__ float x1s[64], x2s[64];
  __shared__ float rs1[16], rs2[16];
  const int t = threadIdx.x;
  for (int p = 15; p >= 0; --p) {
    for (int e = t; e < 4096; e += 1024)
      D[e>>6][e&63] = A[(p*64 + (e>>6))*1024 + p*64 + (e&63)];
    __syncthreads();
    if (t < 64) {
      float v1 = y1g[p*64 + t], v2 = y2g[p*64 + t];
      for (int i = 63; i >= 0; --i) {
        float invd = 1.f / D[i][i];
        float x1 = __shfl(v1, i) * invd;
        float x2 = __shfl(v2, i) * invd;
        float Lim = D[i][t];
        if (t == i)      { v1 = x1; v2 = x2; }
        else if (t < i)  { v1 -= Lim * x1; v2 -= Lim * x2; }
      }
      y1g[p*64 + t] = v1; y2g[p*64 + t] = v2;
      x1s[t] = v1; x2s[t] = v2;
    }
    __syncthreads();
    for (int rr = t; rr < p*64; rr += 1024) {
      float a1 = 0.f, a2 = 0.f;
      #pragma unroll 8
      for (int jj = 0; jj < 64; ++jj) {
        float lv = A[(p*64+jj)*1024 + rr];
        a1 += lv * x1s[jj];
        a2 += lv * x2s[jj];
      }
      y1g[rr] -= a1; y2g[rr] -= a2;
    }
    __syncthreads();
  }
  float s1 = y1g[t], s2 = y2g[t];
  for (int o = 32; o > 0; o >>= 1) { s1 += __shfl_down(s1, o, 64); s2 += __shfl_down(s2, o, 64); }
  if ((t & 63) == 0) { rs1[t >> 6] = s1; rs2[t >> 6] = s2; }
  __syncthreads();
  if (t == 0) {
    float a = 0.f, bb = 0.f;
    #pragma unroll
    for (int w = 0; w < 16; ++w) { a += rs1[w]; bb += rs2[w]; }
    rs1[0] = a / bb;
  }
  __syncthreads();
  const float lam = rs1[0];
  out[t] = y1g[t] - lam * y2g[t];
  for (int e = NM + t; e < NATOM; e += 1024) out[e] = qin[e];
}

// --------------------------------------------------------------- launch
extern "C" void kernel_launch(void* const* d_in, const int* in_sizes, int n_in,
                              void* d_out, int out_size, void* d_ws, size_t ws_size,
                              hipStream_t stream) {
  const float* pos  = (const float*)d_in[0];
  const float* q    = (const float*)d_in[1];
  const float* cell = (const float*)d_in[2];
  float* out = (float*)d_out;

  float* ws  = (float*)d_ws;
  float* A   = ws;                                   // 1,048,576 floats
  float* kx  = ws + 1048576;
  float* ky  = kx + KPAD2;
  float* kz  = ky + KPAD2;
  float* ksw = kz + KPAD2;
  float* gc  = ksw + KPAD2;                          // KPAD2
  float* gs  = gc + KPAD2;                           // KPAD2
  float* r1  = gs + KPAD2;                           // 1024
  float* r2  = r1 + 1024;                            // 1024
  float* y1g = r2 + 1024;                            // 1024
  float* y2g = y1g + 1024;                           // 1024

  sfk<<<NCH, 256, 0, stream>>>(pos, q, cell, kx, ky, kz, ksw, gc, gs);
  fB<<<NM, 256, 0, stream>>>(pos, kx, ky, kz, gc, gs, r1, r2);
  hipMemsetAsync(A, 0, 1024 * 1024 * sizeof(float), stream);
  gemmA<<<36 * KSPLIT, 256, 0, stream>>>(pos, kx, ky, kz, ksw, A);
  for (int p = 0; p < 32; ++p) {
    const int s = 31 - p;
    const int grid = (32 - p) + ((p >= 1) ? s * (s + 1) / 2 : 0);
    step<<<grid, 256, 0, stream>>>(A, r1, r2, r1, r2, y1g, y2g, p);
  }
  bwd_out<<<1, 1024, 0, stream>>>(A, y1g, y2g, q, out);
}

// Round 16
// 887.249 us; speedup vs baseline: 1.3817x; 1.0357x over previous
//
#include <hip/hip_runtime.h>
#include <math.h>

#define NATOM 4096
#define NM    1024
#define NKR   9260      // real k-vectors (21^3 - 1)
#define KSPLIT 14
#define CHPS  22        // chunks per split
#define NCH   308       // KSPLIT*CHPS
#define KC    32
#define KPAD2 9856      // NCH*KC
#define PI_F  3.14159265358979f

typedef short v8s __attribute__((ext_vector_type(8)));   // 8 bf16 (4 VGPRs)
typedef float v4f __attribute__((ext_vector_type(4)));   // 4 fp32

// ---------- k-vector data computed inline (device helper) ----------
static __device__ __forceinline__ void kdata(int t, const float* __restrict__ cell,
                                             float& kxx, float& kyy, float& kzz, float& w) {
  if (t >= NKR) { kxx = 0.f; kyy = 0.f; kzz = 0.f; w = 0.f; return; }
  int u = (t < 4630) ? t : t + 1;       // skip the all-zero triple
  int a = u / 441;
  int rem = u - a * 441;
  int b = rem / 21;
  int c = rem - b * 21;
  float na = (float)(a - 10), nb = (float)(b - 10), nc = (float)(c - 10);
  float m00=cell[0], m01=cell[1], m02=cell[2];
  float m10=cell[3], m11=cell[4], m12=cell[5];
  float m20=cell[6], m21=cell[7], m22=cell[8];
  float det = m00*(m11*m22 - m12*m21) - m01*(m10*m22 - m12*m20) + m02*(m10*m21 - m11*m20);
  float inv00 =  (m11*m22 - m12*m21) / det;
  float inv01 = -(m01*m22 - m02*m21) / det;
  float inv02 =  (m01*m12 - m02*m11) / det;
  float inv10 = -(m10*m22 - m12*m20) / det;
  float inv11 =  (m00*m22 - m02*m20) / det;
  float inv12 = -(m00*m12 - m02*m10) / det;
  float inv20 =  (m10*m21 - m11*m20) / det;
  float inv21 = -(m00*m21 - m01*m20) / det;
  float inv22 =  (m00*m11 - m01*m10) / det;
  const float twopi = 2.f * PI_F;
  kxx = twopi * (na*inv00 + nb*inv01 + nc*inv02);
  kyy = twopi * (na*inv10 + nb*inv11 + nc*inv12);
  kzz = twopi * (na*inv20 + nb*inv21 + nc*inv22);
  float k2 = kxx*kxx + kyy*kyy + kzz*kzz;
  const float sigma = 1.0f / 1.805132f;
  w = (4.f * PI_F / fabsf(det)) * __expf(-0.5f * sigma * sigma * k2) / k2;
}

// ---------- sfk: k-data + structure factors in one kernel.
__global__ __launch_bounds__(256)
void sfk(const float* __restrict__ pos, const float* __restrict__ q,
         const float* __restrict__ cell,
         float* __restrict__ kx, float* __restrict__ ky,
         float* __restrict__ kz, float* __restrict__ ksw,
         float* __restrict__ gc, float* __restrict__ gs) {
  __shared__ float red1[8][32], red2[8][32];
  const int kloc = threadIdx.x & 31;
  const int part = threadIdx.x >> 5;             // 0..7
  const int k = blockIdx.x * 32 + kloc;          // < KPAD2
  float kxx, kyy, kzz, w;
  kdata(k, cell, kxx, kyy, kzz, w);
  if (part == 0) { kx[k]=kxx; ky[k]=kyy; kz[k]=kzz; ksw[k]=sqrtf(w); }
  float sc = 0.f, ss = 0.f;
  const int j0 = NM + part * 384, j1 = j0 + 384;
  for (int j = j0; j < j1; ++j) {
    float kr = kxx*pos[3*j] + kyy*pos[3*j+1] + kzz*pos[3*j+2];
    float s, c;
    __sincosf(kr, &s, &c);
    float qj = q[j];
    sc += qj * c;
    ss += qj * s;
  }
  red1[part][kloc] = sc;
  red2[part][kloc] = ss;
  __syncthreads();
  if (part == 0) {
    float tc = 0.f, ts = 0.f;
    #pragma unroll
    for (int pp = 0; pp < 8; ++pp) { tc += red1[pp][kloc]; ts += red2[pp][kloc]; }
    gc[k] = w * tc;
    gs[k] = w * ts;
  }
}

// ----------------- B = -f at metal positions; also init r2 = ones
__global__ __launch_bounds__(256)
void fB(const float* __restrict__ pos,
        const float* __restrict__ kx, const float* __restrict__ ky,
        const float* __restrict__ kz,
        const float* __restrict__ gc, const float* __restrict__ gs,
        float* __restrict__ r1, float* __restrict__ r2) {
  int i = blockIdx.x;
  float px = pos[3*i], py = pos[3*i+1], pz = pos[3*i+2];
  float p = 0.f;
  for (int k = threadIdx.x; k < KPAD2; k += 256) {
    float kr = kx[k]*px + ky[k]*py + kz[k]*pz;
    float s, c;
    __sincosf(kr, &s, &c);
    p += gc[k]*c + gs[k]*s;
  }
  for (int o = 32; o > 0; o >>= 1) p += __shfl_down(p, o, 64);
  __shared__ float red[4];
  if ((threadIdx.x & 63) == 0) red[threadIdx.x >> 6] = p;
  __syncthreads();
  if (threadIdx.x == 0) {
    r1[i] = -(red[0] + red[1] + red[2] + red[3]);
    r2[i] = 1.f;
  }
}

// --------------- A = C W C^T + S W S^T, upper 128-tiles only (bi<=bj)
// MFMA 3-pass split-bf16 with XOR-swizzled k-group slots (R15 verbatim).
#define PSTR 40
__global__ __launch_bounds__(256, 2)
void gemmA(const float* __restrict__ pos,
           const float* __restrict__ kx, const float* __restrict__ ky,
           const float* __restrict__ kz, const float* __restrict__ ksw,
           float* __restrict__ A) {
  __shared__ short Pl[8][128 * PSTR];
  const int blk = blockIdx.x;
  const int split = blk / 36;
  const int tt = blk - split * 36;
  int bi = 0, rem = tt;
  while (rem >= 8 - bi) { rem -= 8 - bi; ++bi; }
  const int bj = bi + rem;
  const int t = threadIdx.x;
  const int side = t >> 7;
  const int a = t & 127;
  const int atom = (side ? bj : bi) * 128 + a;
  const float px = pos[3*atom], py = pos[3*atom+1], pz = pos[3*atom+2];
  const int axor = (a >> 3) & 3;
  short* PC_hi = &Pl[side*4+0][a*PSTR];
  short* PC_mi = &Pl[side*4+1][a*PSTR];
  short* PS_hi = &Pl[side*4+2][a*PSTR];
  short* PS_mi = &Pl[side*4+3][a*PSTR];

  const int w = t >> 6;          // wave id 0..3 -> rows [w*32, w*32+32)
  const int lane = t & 63;
  const int ln15 = lane & 15;
  const int quad = lane >> 4;

  v4f acc[2][8];
  #pragma unroll
  for (int mt = 0; mt < 2; ++mt)
    #pragma unroll
    for (int nt = 0; nt < 8; ++nt) {
      v4f z = {0.f, 0.f, 0.f, 0.f};
      acc[mt][nt] = z;
    }

  for (int ch = split * CHPS; ch < split * CHPS + CHPS; ++ch) {
    const int kb = ch * KC;
    #pragma unroll
    for (int g = 0; g < 4; ++g) {
      v8s vch, vcm, vsh, vsm;
      #pragma unroll
      for (int j = 0; j < 8; ++j) {
        const int gk = kb + g*8 + j;
        float kr = kx[gk]*px + ky[gk]*py + kz[gk]*pz;
        float s, c;
        __sincosf(kr, &s, &c);
        float sw = ksw[gk];
        float cv = c * sw, sv = s * sw;
        unsigned cu = __float_as_uint(cv);
        float chf = __uint_as_float(cu & 0xffff0000u);
        unsigned cmu = __float_as_uint(cv - chf);
        unsigned su = __float_as_uint(sv);
        float shf = __uint_as_float(su & 0xffff0000u);
        unsigned smu = __float_as_uint(sv - shf);
        vch[j] = (short)(cu >> 16);
        vcm[j] = (short)(cmu >> 16);
        vsh[j] = (short)(su >> 16);
        vsm[j] = (short)(smu >> 16);
      }
      const int slot = (g ^ axor) * 8;
      *(v8s*)&PC_hi[slot] = vch;
      *(v8s*)&PC_mi[slot] = vcm;
      *(v8s*)&PS_hi[slot] = vsh;
      *(v8s*)&PS_mi[slot] = vsm;
    }
    __syncthreads();
    v8s aCh[2], aCm[2], aSh[2], aSm[2];
    #pragma unroll
    for (int mt = 0; mt < 2; ++mt) {
      const int row = w*32 + mt*16 + ln15;
      const int off = row * PSTR + (quad ^ ((row >> 3) & 3)) * 8;
      aCh[mt] = *(const v8s*)&Pl[0][off];
      aCm[mt] = *(const v8s*)&Pl[1][off];
      aSh[mt] = *(const v8s*)&Pl[2][off];
      aSm[mt] = *(const v8s*)&Pl[3][off];
    }
    #pragma unroll
    for (int nt = 0; nt < 8; ++nt) {
      const int row = nt*16 + ln15;
      const int off = row * PSTR + (quad ^ ((row >> 3) & 3)) * 8;
      v8s bCh = *(const v8s*)&Pl[4][off];
      v8s bCm = *(const v8s*)&Pl[5][off];
      v8s bSh = *(const v8s*)&Pl[6][off];
      v8s bSm = *(const v8s*)&Pl[7][off];
      #pragma unroll
      for (int mt = 0; mt < 2; ++mt) {
        v4f d = acc[mt][nt];
        d = __builtin_amdgcn_mfma_f32_16x16x32_bf16(aCh[mt], bCh, d, 0, 0, 0);
        d = __builtin_amdgcn_mfma_f32_16x16x32_bf16(aCh[mt], bCm, d, 0, 0, 0);
        d = __builtin_amdgcn_mfma_f32_16x16x32_bf16(aCm[mt], bCh, d, 0, 0, 0);
        d = __builtin_amdgcn_mfma_f32_16x16x32_bf16(aSh[mt], bSh, d, 0, 0, 0);
        d = __builtin_amdgcn_mfma_f32_16x16x32_bf16(aSh[mt], bSm, d, 0, 0, 0);
        d = __builtin_amdgcn_mfma_f32_16x16x32_bf16(aSm[mt], bSh, d, 0, 0, 0);
        acc[mt][nt] = d;
      }
    }
    __syncthreads();
  }
  #pragma unroll
  for (int mt = 0; mt < 2; ++mt)
    #pragma unroll
    for (int nt = 0; nt < 8; ++nt)
      #pragma unroll
      for (int r = 0; r < 4; ++r) {
        const int row = bi*128 + w*32 + mt*16 + quad*4 + r;
        const int col = bj*128 + nt*16 + ln15;
        atomicAdd(&A[row*1024 + col], acc[mt][nt][r]);
      }
}

// ============ step(p): b=32 panels, fused lazy-syrk + panel (R15 verbatim) ============
__global__ __launch_bounds__(256)
void step(float* __restrict__ A, const float* __restrict__ r1, const float* __restrict__ r2,
          float* __restrict__ ru1, float* __restrict__ ru2,
          float* __restrict__ y1g, float* __restrict__ y2g, int p) {
  __shared__ __align__(16) float D[32][36];
  __shared__ __align__(16) float T[32][36];
  __shared__ float y1s[32], y2s[32];
  const int t = threadIdx.x;
  const int nb = 32 - p;
  const int i0 = (t >> 4) * 2, j0 = (t & 15) * 2;   // 2x2 micro-tile
  const int lr = t >> 3, lc = (t & 7) * 4;          // float4 tile coords

  if ((int)blockIdx.x >= nb) {
    // ---------------- syrk role (only launched for p >= 1) ----------------
    int rem = blockIdx.x - nb, a = 0;
    while (rem >= a + 1) { rem -= (a + 1); ++a; }
    const int qi = p + 1 + a, qj = p + 1 + rem;     // qi >= qj >= p+1
    *(v4f*)&D[lr][lc] = *(const v4f*)&A[(qi*32+lr)*1024 + (p-1)*32 + lc];  // L(qi,p-1)
    *(v4f*)&T[lr][lc] = *(const v4f*)&A[(qj*32+lr)*1024 + (p-1)*32 + lc];  // L(qj,p-1)
    float o[2][2];
    if (p == 1 && (qi >> 2) != (qj >> 2)) {
      #pragma unroll
      for (int ii = 0; ii < 2; ++ii)
        #pragma unroll
        for (int jj = 0; jj < 2; ++jj)
          o[ii][jj] = A[(qj*32 + j0+jj)*1024 + qi*32 + i0+ii];
    } else {
      #pragma unroll
      for (int ii = 0; ii < 2; ++ii)
        #pragma unroll
        for (int jj = 0; jj < 2; ++jj)
          o[ii][jj] = A[(qi*32+i0+ii)*1024 + qj*32 + j0+jj];
    }
    __syncthreads();
    for (int m = 0; m < 32; ++m) {
      float a0 = D[i0][m], a1 = D[i0+1][m];
      float b0 = T[j0][m], b1 = T[j0+1][m];
      o[0][0]-=a0*b0; o[0][1]-=a0*b1;
      o[1][0]-=a1*b0; o[1][1]-=a1*b1;
    }
    #pragma unroll
    for (int ii = 0; ii < 2; ++ii)
      #pragma unroll
      for (int jj = 0; jj < 2; ++jj)
        A[(qi*32+i0+ii)*1024 + qj*32 + j0+jj] = o[ii][jj];
    return;
  }

  // ---------------- panel role: tile (q, p) ----------------
  const int b = blockIdx.x;
  const int q = p + b;
  if (p == 0) {
    *(v4f*)&D[lr][lc] = *(const v4f*)&A[lr*1024 + lc];                    // A(0,0)
    if (b > 0) {
      if (q < 4) {
        *(v4f*)&T[lr][lc] = *(const v4f*)&A[(q*32+lr)*1024 + lc];         // direct
      } else {
        for (int e = t; e < 1024; e += 256)
          T[e&31][e>>5] = A[(e>>5)*1024 + q*32 + (e&31)];                 // A(0,q)^T
      }
    }
    __syncthreads();
  } else {
    *(v4f*)&D[lr][lc] = *(const v4f*)&A[(p*32+lr)*1024 + (p-1)*32 + lc];  // L(p,p-1)
    if (b > 0)
      *(v4f*)&T[lr][lc] = *(const v4f*)&A[(q*32+lr)*1024 + (p-1)*32 + lc];// L(q,p-1)
    __syncthreads();
    // diag update o1 = A(p,p) - L(p,p-1) L(p,p-1)^T
    float o1[2][2];
    #pragma unroll
    for (int ii = 0; ii < 2; ++ii)
      #pragma unroll
      for (int jj = 0; jj < 2; ++jj)
        o1[ii][jj] = A[(p*32+i0+ii)*1024 + p*32 + j0+jj];
    for (int m = 0; m < 32; ++m) {
      float a0 = D[i0][m], a1 = D[i0+1][m];
      float b0 = D[j0][m], b1 = D[j0+1][m];
      o1[0][0]-=a0*b0; o1[0][1]-=a0*b1;
      o1[1][0]-=a1*b0; o1[1][1]-=a1*b1;
    }
    float o2[2][2];
    if (b > 0) {
      // own-tile update o2 = A(q,p) - L(q,p-1) L(p,p-1)^T
      if (p == 1 && (q >> 2) != 0) {
        #pragma unroll
        for (int ii = 0; ii < 2; ++ii)
          #pragma unroll
          for (int jj = 0; jj < 2; ++jj)
            o2[ii][jj] = A[(1*32 + j0+jj)*1024 + q*32 + i0+ii];
      } else {
        #pragma unroll
        for (int ii = 0; ii < 2; ++ii)
          #pragma unroll
          for (int jj = 0; jj < 2; ++jj)
            o2[ii][jj] = A[(q*32+i0+ii)*1024 + p*32 + j0+jj];
      }
      for (int m = 0; m < 32; ++m) {
        float a0 = T[i0][m], a1 = T[i0+1][m];
        float b0 = D[j0][m], b1 = D[j0+1][m];
        o2[0][0]-=a0*b0; o2[0][1]-=a0*b1;
        o2[1][0]-=a1*b0; o2[1][1]-=a1*b1;
      }
    }
    __syncthreads();   // done reading D,T as L-tiles
    #pragma unroll
    for (int ii = 0; ii < 2; ++ii)
      #pragma unroll
      for (int jj = 0; jj < 2; ++jj)
        D[i0+ii][j0+jj] = o1[ii][jj];
    if (b > 0) {
      #pragma unroll
      for (int ii = 0; ii < 2; ++ii)
        #pragma unroll
        for (int jj = 0; jj < 2; ++jj)
          T[i0+ii][j0+jj] = o2[ii][jj];
    }
    __syncthreads();
  }

  // ---- wave-register Cholesky of D (lanes 0..31; lane = row) ----
  if (t < 32) {
    float a[32];
    #pragma unroll
    for (int m = 0; m < 32; ++m) a[m] = D[t][m];
    #pragma unroll
    for (int j = 0; j < 32; ++j) {
      float dj = __shfl(a[j], j);
      float rinv = rsqrtf(dj);
      float lj = (t == j) ? dj * rinv : a[j] * rinv;
      a[j] = lj;
      #pragma unroll
      for (int m = j + 1; m < 32; ++m)
        a[m] -= lj * __shfl(lj, m);
    }
    #pragma unroll
    for (int m = 0; m < 32; ++m) D[t][m] = a[m];  // upper garbage, never read
  }
  __syncthreads();
  if (b == 0) {
    for (int e = t; e < 1024; e += 256) {
      int i = e >> 5, j = e & 31;
      if (i >= j) A[(p*32+i)*1024 + p*32 + j] = D[i][j];
    }
  } else {
    // ---- blocked-register TRSM: solve X L^T = T (lanes 0..31 = rows) ----
    if (t < 32) {
      #pragma unroll
      for (int cb = 0; cb < 2; ++cb) {
        const int cbase = cb * 16;
        float x[16];
        #pragma unroll
        for (int k = 0; k < 16; ++k) x[k] = T[t][cbase + k];
        for (int m = 0; m < cbase; ++m) {
          float tm = T[t][m];                       // own solved value
          #pragma unroll
          for (int k = 0; k < 16; ++k)
            x[k] -= tm * D[cbase + k][m];           // broadcast L read
        }
        #pragma unroll
        for (int k = 0; k < 16; ++k) {
          float xv = x[k] * (1.0f / D[cbase + k][cbase + k]);
          x[k] = xv;
          #pragma unroll
          for (int m2 = k + 1; m2 < 16; ++m2)
            x[m2] -= xv * D[cbase + m2][cbase + k];
        }
        #pragma unroll
        for (int k = 0; k < 16; ++k) T[t][cbase + k] = x[k];
      }
    }
    __syncthreads();
    *(v4f*)&A[(q*32+lr)*1024 + p*32 + lc] = *(const v4f*)&T[lr][lc];
  }
  __syncthreads();
  // forward solve y_p = L_pp^{-1} r_p (redundant per block, lanes 0..31)
  if (t < 32) {
    float v1 = r1[p*32 + t], v2 = r2[p*32 + t];
    for (int j = 0; j < 32; ++j) {
      float invd = 1.f / D[j][j];
      float Lij = D[t][j];
      float x1 = __shfl(v1, j) * invd;
      float x2 = __shfl(v2, j) * invd;
      if (t == j)      { v1 = x1; v2 = x2; }
      else if (t > j)  { v1 -= Lij * x1; v2 -= Lij * x2; }
    }
    y1s[t] = v1; y2s[t] = v2;
    if (b == 0) { y1g[p*32 + t] = v1; y2g[p*32 + t] = v2; }
  }
  __syncthreads();
  if (b > 0 && t < 32) {
    float a1 = 0.f, a2 = 0.f;
    for (int j = 0; j < 32; ++j) {
      float lv = T[t][j];
      a1 += lv * y1s[j];
      a2 += lv * y2s[j];
    }
    ru1[q*32 + t] -= a1;
    ru2[q*32 + t] -= a2;
  }
}

// ------- invd: invert the 16 diagonal 64x64 L blocks in parallel.
// Block k, 64 threads; thread j computes column j of X = L^{-1} (lower).
// Upper parts of the stored diag tiles are garbage -> masked to 0 on load.
__global__ __launch_bounds__(64)
void invd(const float* __restrict__ A, float* __restrict__ iD) {
  __shared__ float Lb[64][65];
  __shared__ float Xs[64][65];
  const int k = blockIdx.x;
  const int j = threadIdx.x;
  const int base = k * 64;
  for (int e = j; e < 4096; e += 64) {
    int r = e >> 6, c = e & 63;
    Lb[r][c] = (r >= c) ? A[(base + r)*1024 + base + c] : 0.f;
  }
  __syncthreads();
  // column j: X[r][j], r from j to 63 (thread-private column, no races)
  for (int r = 0; r < j; ++r) Xs[r][j] = 0.f;
  Xs[j][j] = 1.f / Lb[j][j];
  for (int r = j + 1; r < 64; ++r) {
    float s = 0.f;
    for (int m = j; m < r; ++m) s += Lb[r][m] * Xs[m][j];
    Xs[r][j] = -s / Lb[r][r];
  }
  __syncthreads();
  for (int e = j; e < 4096; e += 64)
    iD[k*4096 + e] = Xs[e>>6][e&63];
}

// --------- backward solve via precomputed invL blocks: per panel p,
// x_p = invL_p^T y_p (GEMV, no dependent chain), then trailing update.
__global__ __launch_bounds__(1024)
void bwd_out(const float* __restrict__ A, const float* __restrict__ iD,
             float* __restrict__ y1g, float* __restrict__ y2g,
             const float* __restrict__ qin, float* __restrict__ out) {
  __shared__ float D[64][65];
  __shared__ float yin1[64], yin2[64];
  __shared__ float x1s[64], x2s[64];
  __shared__ float rs1[16], rs2[16];
  const int t = threadIdx.x;
  for (int p = 15; p >= 0; --p) {
    const int base = p * 64;
    for (int e = t; e < 4096; e += 1024)
      D[e>>6][e&63] = iD[p*4096 + e];
    if (t < 64) { yin1[t] = y1g[base + t]; yin2[t] = y2g[base + t]; }
    __syncthreads();
    if (t < 64) {
      // x[t] = sum_m invL[m][t] * y[m]  (invL stored full, zeros above diag)
      float v1 = 0.f, v2 = 0.f;
      #pragma unroll 8
      for (int m = 0; m < 64; ++m) {
        float w = D[m][t];
        v1 += w * yin1[m];
        v2 += w * yin2[m];
      }
      y1g[base + t] = v1; y2g[base + t] = v2;
      x1s[t] = v1; x2s[t] = v2;
    }
    __syncthreads();
    for (int rr = t; rr < base; rr += 1024) {
      float a1 = 0.f, a2 = 0.f;
      #pragma unroll 8
      for (int jj = 0; jj < 64; ++jj) {
        float lv = A[(base+jj)*1024 + rr];
        a1 += lv * x1s[jj];
        a2 += lv * x2s[jj];
      }
      y1g[rr] -= a1; y2g[rr] -= a2;
    }
    __syncthreads();
  }
  float s1 = y1g[t], s2 = y2g[t];
  for (int o = 32; o > 0; o >>= 1) { s1 += __shfl_down(s1, o, 64); s2 += __shfl_down(s2, o, 64); }
  if ((t & 63) == 0) { rs1[t >> 6] = s1; rs2[t >> 6] = s2; }
  __syncthreads();
  if (t == 0) {
    float a = 0.f, bb = 0.f;
    #pragma unroll
    for (int w = 0; w < 16; ++w) { a += rs1[w]; bb += rs2[w]; }
    rs1[0] = a / bb;
  }
  __syncthreads();
  const float lam = rs1[0];
  out[t] = y1g[t] - lam * y2g[t];
  for (int e = NM + t; e < NATOM; e += 1024) out[e] = qin[e];
}

// --------------------------------------------------------------- launch
extern "C" void kernel_launch(void* const* d_in, const int* in_sizes, int n_in,
                              void* d_out, int out_size, void* d_ws, size_t ws_size,
                              hipStream_t stream) {
  const float* pos  = (const float*)d_in[0];
  const float* q    = (const float*)d_in[1];
  const float* cell = (const float*)d_in[2];
  float* out = (float*)d_out;

  float* ws  = (float*)d_ws;
  float* A   = ws;                                   // 1,048,576 floats
  float* kx  = ws + 1048576;
  float* ky  = kx + KPAD2;
  float* kz  = ky + KPAD2;
  float* ksw = kz + KPAD2;
  float* gc  = ksw + KPAD2;                          // KPAD2
  float* gs  = gc + KPAD2;                           // KPAD2
  float* r1  = gs + KPAD2;                           // 1024
  float* r2  = r1 + 1024;                            // 1024
  float* y1g = r2 + 1024;                            // 1024
  float* y2g = y1g + 1024;                           // 1024
  float* iD  = y2g + 1024;                           // 16 * 4096

  sfk<<<NCH, 256, 0, stream>>>(pos, q, cell, kx, ky, kz, ksw, gc, gs);
  fB<<<NM, 256, 0, stream>>>(pos, kx, ky, kz, gc, gs, r1, r2);
  hipMemsetAsync(A, 0, 1024 * 1024 * sizeof(float), stream);
  gemmA<<<36 * KSPLIT, 256, 0, stream>>>(pos, kx, ky, kz, ksw, A);
  for (int p = 0; p < 32; ++p) {
    const int s = 31 - p;
    const int grid = (32 - p) + ((p >= 1) ? s * (s + 1) / 2 : 0);
    step<<<grid, 256, 0, stream>>>(A, r1, r2, r1, r2, y1g, y2g, p);
  }
  invd<<<16, 64, 0, stream>>>(A, iD);
  bwd_out<<<1, 1024, 0, stream>>>(A, iD, y1g, y2g, q, out);
}